// Round 4
// baseline (190.781 us; speedup 1.0000x reference)
//
#include <hip/hip_runtime.h>

// Greedy CTC decode, single fused dispatch.
//   index[t] = argmax_v emission[t, v]   (first occurrence on ties)
//   keep[t]  = (index[t] != 0) && (t == 0 || index[t] != index[t-1])
// (reference's char mapping is injective in index, so index comparison is
//  equivalent to char comparison; blank <=> index==0)
//
// d_out (int32): [0, T) = index, [T, 2T) = keep (0/1).
//
// Layout: 2048 blocks x 256 threads (4 waves). Block b owns rows
// [32b, 32b+32); wave w owns 8 contiguous rows. Cross-block keep dependency
// (idx[32b-1]) is resolved by wave 0 redundantly computing row 32b-1
// (+3.1% reads, saves a second dispatch).

#define T_ROWS 65536
#define V_LABELS 512
#define RPW 8                  // rows per wave
#define WPB 4                  // waves per block
#define RPB (RPW * WPB)        // 32 rows per block
#define NBLOCKS (T_ROWS / RPB) // 2048

__device__ __forceinline__ int argmax_row(const float* __restrict__ em,
                                          int row, int lane) {
    const float4* rp =
        reinterpret_cast<const float4*>(em + (size_t)row * V_LABELS);
    // two fully-coalesced float4 loads per lane (elems 4i..4i+3, 256+4i..)
    float4 a = rp[lane];
    float4 b = rp[lane + 64];

    float bv = a.x;
    int bi = 4 * lane;
    // ascending index order + strict '>' keeps the FIRST max per lane
    if (a.y > bv) { bv = a.y; bi = 4 * lane + 1; }
    if (a.z > bv) { bv = a.z; bi = 4 * lane + 2; }
    if (a.w > bv) { bv = a.w; bi = 4 * lane + 3; }
    if (b.x > bv) { bv = b.x; bi = 256 + 4 * lane; }
    if (b.y > bv) { bv = b.y; bi = 256 + 4 * lane + 1; }
    if (b.z > bv) { bv = b.z; bi = 256 + 4 * lane + 2; }
    if (b.w > bv) { bv = b.w; bi = 256 + 4 * lane + 3; }

    // 64-lane butterfly; tie-break: smaller index wins
    #pragma unroll
    for (int m = 1; m < 64; m <<= 1) {
        float ov = __shfl_xor(bv, m, 64);
        int   oi = __shfl_xor(bi, m, 64);
        if (ov > bv || (ov == bv && oi < bi)) { bv = ov; bi = oi; }
    }
    return bi;  // uniform across the wave
}

__global__ __launch_bounds__(256) void ctc_fused_kernel(
    const float* __restrict__ em, int* __restrict__ out_idx,
    int* __restrict__ out_keep) {
    const int lane = threadIdx.x & 63;
    const int w    = threadIdx.x >> 6;
    const int blockBase = blockIdx.x * RPB;
    const int waveBase  = blockBase + w * RPW;

    __shared__ int s_last[WPB];   // last-row idx per wave
    __shared__ int s_prevblock;   // idx[blockBase-1] (or -2 sentinel)

    // wave 0: redundantly compute the row preceding this block
    int prevIdx = -2;  // sentinel (never equals a real index >= 0)
    if (w == 0 && blockIdx.x > 0)
        prevIdx = argmax_row(em, blockBase - 1, lane);

    // argmax for my 8 rows (fully unrolled; static register indexing only)
    int idxs[RPW];
    #pragma unroll
    for (int r = 0; r < RPW; ++r)
        idxs[r] = argmax_row(em, waveBase + r, lane);

    if (lane == 0) {
        s_last[w] = idxs[RPW - 1];
        if (w == 0) s_prevblock = prevIdx;
    }
    __syncthreads();

    // keep: prev index entering this wave's chunk
    int prev = (w > 0) ? s_last[w - 1] : s_prevblock;

    // gather row r's (idx, keep) into lane r via compile-time-indexed selects
    int my_idx = 0, my_keep = 0;
    #pragma unroll
    for (int r = 0; r < RPW; ++r) {
        const int cur = idxs[r];
        const int k   = (cur != 0 && cur != prev) ? 1 : 0;
        if (lane == r) { my_idx = cur; my_keep = k; }
        prev = cur;
    }
    if (lane < RPW) {
        out_idx[waveBase + lane]  = my_idx;
        out_keep[waveBase + lane] = my_keep;
    }
}

extern "C" void kernel_launch(void* const* d_in, const int* in_sizes, int n_in,
                              void* d_out, int out_size, void* d_ws, size_t ws_size,
                              hipStream_t stream) {
    const float* em = (const float*)d_in[0];
    int* out = (int*)d_out;
    ctc_fused_kernel<<<NBLOCKS, 256, 0, stream>>>(em, out, out + T_ROWS);
}

// Round 5
// 187.419 us; speedup vs baseline: 1.0179x; 1.0179x over previous
//
#include <hip/hip_runtime.h>

// Greedy CTC decode, two dispatches (fused version measured WORSE, R4).
//   index[t] = argmax_v emission[t, v]   (first occurrence on ties)
//   keep[t]  = (index[t] != 0) && (t == 0 || index[t] != index[t-1])
// (reference's char mapping is injective in index => index comparison
//  is equivalent to char comparison; blank <=> index==0)
//
// d_out (int32): [0, T) = index, [T, 2T) = keep (0/1).
//
// argmax: one 64-lane wave per 4 rows; all 8 float4 loads issued up-front
// for memory-level parallelism, then 4 independent butterfly reduces.

#define T_ROWS 65536
#define V_LABELS 512
#define RPW 4                            // rows per wave
#define WPB 4                            // waves per 256-thread block
#define NBLOCKS (T_ROWS / (RPW * WPB))   // 4096

__global__ __launch_bounds__(256) void ctc_argmax_kernel(
    const float* __restrict__ em, int* __restrict__ out_idx) {
    const int wave = (blockIdx.x * blockDim.x + threadIdx.x) >> 6;
    const int lane = threadIdx.x & 63;
    const int row0 = wave * RPW;

    // issue all 8 coalesced float4 loads first (4 rows x 2 halves)
    float4 a[RPW], b[RPW];
    #pragma unroll
    for (int r = 0; r < RPW; ++r) {
        const float4* rp = reinterpret_cast<const float4*>(
            em + (size_t)(row0 + r) * V_LABELS);
        a[r] = rp[lane];
        b[r] = rp[lane + 64];
    }

    #pragma unroll
    for (int r = 0; r < RPW; ++r) {
        float bv = a[r].x;
        int bi = 4 * lane;
        // ascending index order + strict '>' keeps the FIRST max per lane
        if (a[r].y > bv) { bv = a[r].y; bi = 4 * lane + 1; }
        if (a[r].z > bv) { bv = a[r].z; bi = 4 * lane + 2; }
        if (a[r].w > bv) { bv = a[r].w; bi = 4 * lane + 3; }
        if (b[r].x > bv) { bv = b[r].x; bi = 256 + 4 * lane; }
        if (b[r].y > bv) { bv = b[r].y; bi = 256 + 4 * lane + 1; }
        if (b[r].z > bv) { bv = b[r].z; bi = 256 + 4 * lane + 2; }
        if (b[r].w > bv) { bv = b[r].w; bi = 256 + 4 * lane + 3; }

        // 64-lane butterfly; tie-break: smaller index wins
        #pragma unroll
        for (int m = 1; m < 64; m <<= 1) {
            float ov = __shfl_xor(bv, m, 64);
            int   oi = __shfl_xor(bi, m, 64);
            if (ov > bv || (ov == bv && oi < bi)) { bv = ov; bi = oi; }
        }
        if (lane == r) out_idx[row0 + r] = bi;  // lane r holds row r's result
    }
}

__global__ __launch_bounds__(256) void ctc_keep_kernel(
    const int* __restrict__ idx, int* __restrict__ keep) {
    const int t = blockIdx.x * blockDim.x + threadIdx.x;
    if (t >= T_ROWS) return;
    const int cur = idx[t];
    bool k;
    if (t == 0) {
        k = (cur != 0);                      // prev sentinel -2 never matches
    } else {
        const int prev = idx[t - 1];
        k = (cur != 0) && (cur != prev);
    }
    keep[t] = k ? 1 : 0;
}

extern "C" void kernel_launch(void* const* d_in, const int* in_sizes, int n_in,
                              void* d_out, int out_size, void* d_ws, size_t ws_size,
                              hipStream_t stream) {
    const float* em = (const float*)d_in[0];
    int* out = (int*)d_out;
    int* out_idx  = out;           // [0, T)
    int* out_keep = out + T_ROWS;  // [T, 2T)

    ctc_argmax_kernel<<<NBLOCKS, 256, 0, stream>>>(em, out_idx);

    const int grid_keep = (T_ROWS + 255) / 256;  // 256
    ctc_keep_kernel<<<grid_keep, 256, 0, stream>>>(out_idx, out_keep);
}